// Round 8
// baseline (5978.763 us; speedup 1.0000x reference)
//
#include <hip/hip_runtime.h>

#define NPTS 256
#define NBATCH 64
#define BIGF 1e30f

__device__ __forceinline__ float rlane(float v, int l) {
    return __uint_as_float((unsigned int)__builtin_amdgcn_readlane((int)__float_as_uint(v), l));
}
__device__ __forceinline__ int rlanei(int v, int l) {
    return __builtin_amdgcn_readlane(v, l);
}
__device__ __forceinline__ float rawsqrt(float x) {
    return __builtin_amdgcn_sqrtf(x);
}

#define DPP_UMIN(v, ctrl) \
    (min)((v), (unsigned int)__builtin_amdgcn_update_dpp( \
        (int)(v), (int)(v), (ctrl), 0xf, 0xf, false))

// Full-wave u32 min; uniform result via lane-63 readlane. (R5-proven.)
__device__ __forceinline__ unsigned int wave_umin_bcast(unsigned int v) {
    v = DPP_UMIN(v, 0x111);   // row_shr:1
    v = DPP_UMIN(v, 0x112);   // row_shr:2
    v = DPP_UMIN(v, 0x114);   // row_shr:4
    v = DPP_UMIN(v, 0x118);   // row_shr:8
    v = DPP_UMIN(v, 0x142);   // row_bcast:15
    v = DPP_UMIN(v, 0x143);   // row_bcast:31
    return (unsigned int)rlanei((int)v, 63);
}

__global__ void zero_out_kernel(float* out, int n) {
    int i = blockIdx.x * blockDim.x + threadIdx.x;
    if (i < n) out[i] = 0.0f;
}

// Per-batch state; lane owns columns/rows {lane, 64+lane, 128+lane, 192+lane}.
struct Bat {
    float prx[4], pry[4], prz[4];      // pred (row) points
    float tx[4], ty[4], tz[4];         // target (col) points
    float vv[4], upc[4], Mv[4], Tv[4];
    float rxc[4], ryc[4], rzc[4];      // matched-row coords, column-attached
    int   pc[4], way[4];
    unsigned long long freem[4];       // free-COLUMN masks (wave-uniform)
    unsigned long long frm[4];         // free-ROW masks (searches pending)
    int   rowi;                        // current search root row
    float rootx, rooty, rootz;
    float bx, by, bz, ukey;            // tree-expansion row state
    int   j0;
    int   usedm;
    int   active;
};

__device__ __forceinline__ void read_point(const float (&x)[4], const float (&y)[4],
                                           const float (&z)[4], int slot, int l,
                                           float& ox, float& oy, float& oz) {
    switch (slot) {
        case 0:  ox = rlane(x[0], l); oy = rlane(y[0], l); oz = rlane(z[0], l); break;
        case 1:  ox = rlane(x[1], l); oy = rlane(y[1], l); oz = rlane(z[1], l); break;
        case 2:  ox = rlane(x[2], l); oy = rlane(y[2], l); oz = rlane(z[2], l); break;
        default: ox = rlane(x[3], l); oy = rlane(y[3], l); oz = rlane(z[3], l); break;
    }
}

// Load + column reduction + greedy claim. (R5-proven structure.)
__device__ __forceinline__ void bat_init(Bat& S, const float* pb, const float* tb, int lane) {
#pragma unroll
    for (int c = 0; c < 4; ++c) {
        int idx = c * 64 + lane;
        S.prx[c] = pb[idx * 3 + 0]; S.pry[c] = pb[idx * 3 + 1]; S.prz[c] = pb[idx * 3 + 2];
        S.tx[c]  = tb[idx * 3 + 0]; S.ty[c]  = tb[idx * 3 + 1]; S.tz[c]  = tb[idx * 3 + 2];
        S.upc[c] = 0.f; S.Tv[c] = 0.f;
        S.rxc[c] = 0.f; S.ryc[c] = 0.f; S.rzc[c] = 0.f;
        S.pc[c] = -1;
    }
    float colmin[4] = {BIGF, BIGF, BIGF, BIGF};
    int   colrow[4] = {0, 0, 0, 0};
#pragma unroll
    for (int rs = 0; rs < 4; ++rs) {
        for (int rl = 0; rl < 64; ++rl) {
            float bx, by, bz;
            read_point(S.prx, S.pry, S.prz, rs, rl, bx, by, bz);
            int r = rs * 64 + rl;
#pragma unroll
            for (int c = 0; c < 4; ++c) {
                float dx = bx - S.tx[c], dy = by - S.ty[c], dz = bz - S.tz[c];
                float d = rawsqrt(dx * dx + dy * dy + dz * dz);
                if (d < colmin[c]) { colmin[c] = d; colrow[c] = r; }
            }
        }
    }
#pragma unroll
    for (int c = 0; c < 4; ++c) { S.vv[c] = colmin[c]; S.freem[c] = ~0ull; S.frm[c] = ~0ull; }

    // Greedy claim: column (ascending) claims its argmin row if row still free.
#pragma unroll
    for (int cs = 0; cs < 4; ++cs) {
        for (int l = 0; l < 64; ++l) {
            int r = rlanei(colrow[cs], l);
            int rs = r >> 6, rl2 = r & 63;
            unsigned long long bit = 1ull << rl2;
            bool free_row = ((rs == 0 ? S.frm[0] : rs == 1 ? S.frm[1] : rs == 2 ? S.frm[2] : S.frm[3]) & bit) != 0ull;
            if (free_row) {
#pragma unroll
                for (int s = 0; s < 4; ++s)
                    if (s == rs) S.frm[s] &= ~bit;
                float bx, by, bz;
                read_point(S.prx, S.pry, S.prz, rs, rl2, bx, by, bz);
                if (lane == l) {
                    S.pc[cs] = r; S.upc[cs] = 0.f;
                    S.rxc[cs] = bx; S.ryc[cs] = by; S.rzc[cs] = bz;
                }
#pragma unroll
                for (int s = 0; s < 4; ++s)
                    if (s == cs) S.freem[s] &= ~(1ull << l);   // column cs*64+l matched
            }
        }
    }
    S.active = 1;
    S.rowi = -1;
    S.bx = S.by = S.bz = 0.f; S.ukey = 0.f; S.j0 = -1; S.usedm = 0;
#pragma unroll
    for (int c = 0; c < 4; ++c) S.Mv[c] = BIGF;
}

// Advance to next free row; reset search state. Sets active=0 when done.
__device__ __forceinline__ void bat_next(Bat& S, int lane) {
    int w;
    if      (S.frm[0]) w = 0;
    else if (S.frm[1]) w = 1;
    else if (S.frm[2]) w = 2;
    else if (S.frm[3]) w = 3;
    else { S.active = 0; return; }
    unsigned long long mm = (w == 0 ? S.frm[0] : w == 1 ? S.frm[1] : w == 2 ? S.frm[2] : S.frm[3]);
    const int il = (int)__builtin_ctzll(mm);
    mm &= mm - 1;
    switch (w) { case 0: S.frm[0] = mm; break; case 1: S.frm[1] = mm; break;
                 case 2: S.frm[2] = mm; break; default: S.frm[3] = mm; break; }
    S.rowi = w * 64 + il;
    read_point(S.prx, S.pry, S.prz, w, il, S.rootx, S.rooty, S.rootz);
    S.bx = S.rootx; S.by = S.rooty; S.bz = S.rootz;
    S.ukey = 0.f; S.j0 = -1; S.usedm = 0;
#pragma unroll
    for (int c = 0; c < 4; ++c) S.Mv[c] = BIGF;
}

// Branchless expansion compute: slack update + key fold + wave reduce.
__device__ __forceinline__ unsigned int bat_part1(Bat& S, const unsigned int (&colu)[4]) {
    float t[4];
#pragma unroll
    for (int c = 0; c < 4; ++c) t[c] = S.vv[c] + S.ukey;
    unsigned int kmin = 0xFFFFFFFFu;
#pragma unroll
    for (int c = 0; c < 4; ++c) {
        float dx = S.bx - S.tx[c], dy = S.by - S.ty[c], dz = S.bz - S.tz[c];
        float d = rawsqrt(dx * dx + dy * dy + dz * dz);
        float cand = d - t[c];
        const bool fr = !((S.usedm >> c) & 1);
        if (fr && cand < S.Mv[c]) { S.Mv[c] = cand; S.way[c] = S.j0; }
        unsigned int key = fr ? ((__float_as_uint(S.Mv[c]) & 0xFFFFFF00u) | colu[c])
                              : 0xFFFFFFFFu;
        kmin = (min)(kmin, key);
    }
    return wave_umin_bcast(kmin);
}

// Commit duals + augment alternating path + clear free-column bit. (Cold.)
__device__ __forceinline__ void bat_augment(Bat& S, int jfin, float D, int lane) {
#pragma unroll
    for (int c = 0; c < 4; ++c)
        if ((S.usedm >> c) & 1) { S.vv[c] += S.Tv[c] - D; S.upc[c] += D - S.Tv[c]; }
    {
        const int w = jfin >> 6;
        const unsigned long long bit = 1ull << (jfin & 63);
#pragma unroll
        for (int s = 0; s < 4; ++s)
            if (s == w) S.freem[s] &= ~bit;
    }
    int jc = jfin;
    while (true) {
        const int osl = jc >> 6, oln = jc & 63;
        int jw;
        switch (osl) {
            case 0:  jw = rlanei(S.way[0], oln); break;
            case 1:  jw = rlanei(S.way[1], oln); break;
            case 2:  jw = rlanei(S.way[2], oln); break;
            default: jw = rlanei(S.way[3], oln); break;
        }
        int np_; float nup, nrx, nry, nrz;
        if (jw < 0) {
            np_ = S.rowi; nup = D; nrx = S.rootx; nry = S.rooty; nrz = S.rootz;
        } else {
            const int wsl = jw >> 6, wln = jw & 63;
            switch (wsl) {
                case 0:  np_ = rlanei(S.pc[0], wln); nup = rlane(S.upc[0], wln); nrx = rlane(S.rxc[0], wln); nry = rlane(S.ryc[0], wln); nrz = rlane(S.rzc[0], wln); break;
                case 1:  np_ = rlanei(S.pc[1], wln); nup = rlane(S.upc[1], wln); nrx = rlane(S.rxc[1], wln); nry = rlane(S.ryc[1], wln); nrz = rlane(S.rzc[1], wln); break;
                case 2:  np_ = rlanei(S.pc[2], wln); nup = rlane(S.upc[2], wln); nrx = rlane(S.rxc[2], wln); nry = rlane(S.ryc[2], wln); nrz = rlane(S.rzc[2], wln); break;
                default: np_ = rlanei(S.pc[3], wln); nup = rlane(S.upc[3], wln); nrx = rlane(S.rxc[3], wln); nry = rlane(S.ryc[3], wln); nrz = rlane(S.rzc[3], wln); break;
            }
        }
#pragma unroll
        for (int c = 0; c < 4; ++c)
            if (c == osl && lane == oln) {
                S.pc[c] = np_; S.upc[c] = nup;
                S.rxc[c] = nrx; S.ryc[c] = nry; S.rzc[c] = nrz;
            }
        if (jw < 0) break;
        jc = jw;
    }
}

// Selection + tree growth / search termination.
__device__ __forceinline__ void bat_part2(Bat& S, unsigned int kk, int lane) {
    const int   j1   = (int)(kk & 0xFFu);
    const float gmin = __uint_as_float(kk & 0xFFFFFF00u);
    const int osl = j1 >> 6, oln = j1 & 63;

    const unsigned long long fm =
        (osl == 0 ? S.freem[0] : osl == 1 ? S.freem[1] : osl == 2 ? S.freem[2] : S.freem[3]);
    if ((fm >> oln) & 1ull) {               // selected column is free: augment
        bat_augment(S, j1, gmin, lane);
        bat_next(S, lane);
        return;
    }
    float uj, nbx, nby, nbz;
    switch (osl) {
        case 0:  uj = rlane(S.upc[0], oln); nbx = rlane(S.rxc[0], oln); nby = rlane(S.ryc[0], oln); nbz = rlane(S.rzc[0], oln); break;
        case 1:  uj = rlane(S.upc[1], oln); nbx = rlane(S.rxc[1], oln); nby = rlane(S.ryc[1], oln); nbz = rlane(S.rzc[1], oln); break;
        case 2:  uj = rlane(S.upc[2], oln); nbx = rlane(S.rxc[2], oln); nby = rlane(S.ryc[2], oln); nbz = rlane(S.rzc[2], oln); break;
        default: uj = rlane(S.upc[3], oln); nbx = rlane(S.rxc[3], oln); nby = rlane(S.ryc[3], oln); nbz = rlane(S.rzc[3], oln); break;
    }
#pragma unroll
    for (int c = 0; c < 4; ++c)
        if (c == osl && lane == oln) { S.usedm |= (1 << c); S.Tv[c] = gmin; }
    S.bx = nbx; S.by = nby; S.bz = nbz;
    S.ukey = uj - gmin;
    S.j0 = j1;
}

__device__ __forceinline__ float bat_cost(const Bat& S) {
    float s = 0.f;
#pragma unroll
    for (int c = 0; c < 4; ++c) {
        float dx = S.rxc[c] - S.tx[c], dy = S.ryc[c] - S.ty[c], dz = S.rzc[c] - S.tz[c];
        s += sqrtf(dx * dx + dy * dy + dz * dz);
    }
    return s;
}

// Two batches per wave: the two expansion-step compute chains (part1) are
// independent and sit in one basic block -> their ~170cy latency chains
// overlap, nearly doubling throughput of this latency-bound loop.
__launch_bounds__(64, 1)
__global__ void hungarian_wave2(const float* __restrict__ pred,
                                const float* __restrict__ target,
                                float* __restrict__ out) {
    const int bb   = blockIdx.x;        // 0..31 -> batches 2bb, 2bb+1
    const int lane = threadIdx.x;

    unsigned int colu[4];
#pragma unroll
    for (int c = 0; c < 4; ++c) colu[c] = (unsigned int)(c * 64 + lane);

    Bat A, B;
    bat_init(A, pred + (size_t)(2 * bb)     * NPTS * 3, target + (size_t)(2 * bb)     * NPTS * 3, lane);
    bat_init(B, pred + (size_t)(2 * bb + 1) * NPTS * 3, target + (size_t)(2 * bb + 1) * NPTS * 3, lane);
    bat_next(A, lane);
    bat_next(B, lane);

    while (A.active | B.active) {
        unsigned int kkA = bat_part1(A, colu);   // independent chains,
        unsigned int kkB = bat_part1(B, colu);   // same basic block -> overlap
        if (A.active) bat_part2(A, kkA, lane);
        if (B.active) bat_part2(B, kkB, lane);
    }

    float s = bat_cost(A) + bat_cost(B);
#pragma unroll
    for (int off = 1; off < 64; off <<= 1) s += __shfl_xor(s, off, 64);
    if (lane == 0) atomicAdd(out, s / (float)NBATCH);
}

extern "C" void kernel_launch(void* const* d_in, const int* in_sizes, int n_in,
                              void* d_out, int out_size, void* d_ws, size_t ws_size,
                              hipStream_t stream) {
    const float* pred   = (const float*)d_in[0];
    const float* target = (const float*)d_in[1];
    float* out = (float*)d_out;

    zero_out_kernel<<<1, 64, 0, stream>>>(out, out_size);
    hungarian_wave2<<<NBATCH / 2, 64, 0, stream>>>(pred, target, out);
}

// Round 9
// 2007.483 us; speedup vs baseline: 2.9782x; 2.9782x over previous
//
#include <hip/hip_runtime.h>

#define NPTS 256
#define NBATCH 64
#define BIGF 1e30f

__device__ __forceinline__ float rlane(float v, int l) {
    return __uint_as_float((unsigned int)__builtin_amdgcn_readlane((int)__float_as_uint(v), l));
}
__device__ __forceinline__ int rlanei(int v, int l) {
    return __builtin_amdgcn_readlane(v, l);
}
__device__ __forceinline__ float rawsqrt(float x) {
    return __builtin_amdgcn_sqrtf(x);
}

// Uniform-slot select (slot wave-uniform); cold paths only.
#define SEL4(a, s) ((s) == 0 ? a[0] : (s) == 1 ? a[1] : (s) == 2 ? a[2] : a[3])

#define DPP_UMIN(v, ctrl) \
    (min)((v), (unsigned int)__builtin_amdgcn_update_dpp( \
        (int)(v), (int)(v), (ctrl), 0xf, 0xf, false))

// Full-wave u32 min; uniform result via lane-63 readlane. (R5-proven.)
__device__ __forceinline__ unsigned int wave_umin_bcast(unsigned int v) {
    v = DPP_UMIN(v, 0x111);   // row_shr:1
    v = DPP_UMIN(v, 0x112);   // row_shr:2
    v = DPP_UMIN(v, 0x114);   // row_shr:4
    v = DPP_UMIN(v, 0x118);   // row_shr:8
    v = DPP_UMIN(v, 0x142);   // row_bcast:15
    v = DPP_UMIN(v, 0x143);   // row_bcast:31
    return (unsigned int)rlanei((int)v, 63);
}

__global__ void zero_out_kernel(float* out, int n) {
    int i = blockIdx.x * blockDim.x + threadIdx.x;
    if (i < n) out[i] = 0.0f;
}

// One wave per batch; lane owns columns/rows {lane, 64+lane, 128+lane, 192+lane}.
// JV: column reduction -> greedy claim -> delta-accumulated Dijkstra searches.
// Monolithic (no structs: R8's struct form spilled to scratch, 3x regression).
// Chain cuts vs R5: SALU free-test on wave-uniform freem masks (no dependent
// pc readlane), w[] = (gmin-uj)-vv reformulation (loop-top adjust off-path),
// Tv dual-deferral. No LDS, no barriers.
__launch_bounds__(64, 1)
__global__ void hungarian_wave(const float* __restrict__ pred,
                               const float* __restrict__ target,
                               float* __restrict__ out) {
    const int b    = blockIdx.x;
    const int lane = threadIdx.x;

    const float* pb = pred   + (size_t)b * NPTS * 3;
    const float* tb = target + (size_t)b * NPTS * 3;

    float prx[4], pry[4], prz[4];      // pred (row) points, row = c*64+lane
    float tx[4], ty[4], tz[4];         // target (col) points, col = c*64+lane
    float vv[4], upc[4], Mv[4], Tv[4], w[4];
    float rxc[4], ryc[4], rzc[4];      // matched-row coords, column-attached
    int   pc[4]  = {-1, -1, -1, -1};   // matched row per column (-1 = free)
    int   way[4];
    unsigned int colu[4];              // this lane's column ids
    unsigned long long freem[4];       // free-COLUMN masks (wave-uniform)

#pragma unroll
    for (int c = 0; c < 4; ++c) {
        int idx = c * 64 + lane;
        prx[c] = pb[idx * 3 + 0]; pry[c] = pb[idx * 3 + 1]; prz[c] = pb[idx * 3 + 2];
        tx[c]  = tb[idx * 3 + 0]; ty[c]  = tb[idx * 3 + 1]; tz[c]  = tb[idx * 3 + 2];
        upc[c] = 0.f; Tv[c] = 0.f;
        rxc[c] = 0.f; ryc[c] = 0.f; rzc[c] = 0.f;
        colu[c] = (unsigned int)idx;
        freem[c] = ~0ull;
    }

    // ---- Phase 1a: column reduction. vv[c] = min_r d(r, col), colrow = argmin ----
    float colmin[4] = {BIGF, BIGF, BIGF, BIGF};
    int   colrow[4] = {0, 0, 0, 0};
#pragma unroll
    for (int rs = 0; rs < 4; ++rs) {
        for (int rl = 0; rl < 64; ++rl) {
            float bx = rlane(prx[rs], rl), by = rlane(pry[rs], rl), bz = rlane(prz[rs], rl);
            int r = rs * 64 + rl;
#pragma unroll
            for (int c = 0; c < 4; ++c) {
                float dx = bx - tx[c], dy = by - ty[c], dz = bz - tz[c];
                float d = rawsqrt(dx * dx + dy * dy + dz * dz);
                if (d < colmin[c]) { colmin[c] = d; colrow[c] = r; }
            }
        }
    }
#pragma unroll
    for (int c = 0; c < 4; ++c) vv[c] = colmin[c];

    // ---- Phase 1b: greedy claim — column (ascending) claims its argmin row if free ----
    unsigned long long frm[4];         // free-row masks (wave-uniform values)
    frm[0] = frm[1] = frm[2] = frm[3] = ~0ull;
#pragma unroll
    for (int cs = 0; cs < 4; ++cs) {
        for (int l = 0; l < 64; ++l) {
            int r = rlanei(colrow[cs], l);
            int rs = r >> 6, rl2 = r & 63;
            unsigned long long bit = 1ull << rl2;
            bool free_row = (SEL4(frm, rs) & bit) != 0ull;
            if (free_row) {
#pragma unroll
                for (int s = 0; s < 4; ++s)
                    if (s == rs) frm[s] &= ~bit;
                float bx, by, bz;
                switch (rs) {
                    case 0:  bx = rlane(prx[0], rl2); by = rlane(pry[0], rl2); bz = rlane(prz[0], rl2); break;
                    case 1:  bx = rlane(prx[1], rl2); by = rlane(pry[1], rl2); bz = rlane(prz[1], rl2); break;
                    case 2:  bx = rlane(prx[2], rl2); by = rlane(pry[2], rl2); bz = rlane(prz[2], rl2); break;
                    default: bx = rlane(prx[3], rl2); by = rlane(pry[3], rl2); bz = rlane(prz[3], rl2); break;
                }
                if (lane == l) {
                    pc[cs] = r; upc[cs] = 0.f;
                    rxc[cs] = bx; ryc[cs] = by; rzc[cs] = bz;
                }
#pragma unroll
                for (int s = 0; s < 4; ++s)
                    if (s == cs) freem[s] &= ~(1ull << l);   // column cs*64+l matched
            }
        }
    }

    // ---- Phase 2: Dijkstra shortest-path for remaining free rows ----
#pragma unroll
    for (int is = 0; is < 4; ++is) {
        unsigned long long m = frm[is];
        while (m) {
            const int il = (int)__builtin_ctzll(m);
            m &= (m - 1);
            const int i = is * 64 + il;

            float rootx, rooty, rootz;
            switch (is) {
                case 0:  rootx = rlane(prx[0], il); rooty = rlane(pry[0], il); rootz = rlane(prz[0], il); break;
                case 1:  rootx = rlane(prx[1], il); rooty = rlane(pry[1], il); rootz = rlane(prz[1], il); break;
                case 2:  rootx = rlane(prx[2], il); rooty = rlane(pry[2], il); rootz = rlane(prz[2], il); break;
                default: rootx = rlane(prx[3], il); rooty = rlane(pry[3], il); rootz = rlane(prz[3], il); break;
            }

#pragma unroll
            for (int c = 0; c < 4; ++c) { Mv[c] = BIGF; w[c] = -vv[c]; }
            int usedm = 0;

            float bx = rootx, by = rooty, bz = rootz;
            int j0 = -1;
            int jfin = 0;
            float D = 0.f;

            while (true) {
                unsigned int kmin = 0xFFFFFFFFu;
#pragma unroll
                for (int c = 0; c < 4; ++c) {
                    float dx = bx - tx[c], dy = by - ty[c], dz = bz - tz[c];
                    float d = rawsqrt(dx * dx + dy * dy + dz * dz);
                    float cand = d + w[c];              // == d - ukey - vv[c]
                    const bool fr = !((usedm >> c) & 1);
                    if (fr && cand < Mv[c]) { Mv[c] = cand; way[c] = j0; }
                    unsigned int key = fr ? ((__float_as_uint(Mv[c]) & 0xFFFFFF00u) | colu[c])
                                          : 0xFFFFFFFFu;
                    kmin = (min)(kmin, key);
                }
                const unsigned int kk = wave_umin_bcast(kmin);
                const int   j1   = (int)(kk & 0xFFu);
                const float gmin = __uint_as_float(kk & 0xFFFFFF00u);
                const int osl = j1 >> 6, oln = j1 & 63;

                // Speculative state readlanes (issued before the exit branch)
                float uj, nbx, nby, nbz;
                switch (osl) {
                    case 0:  uj = rlane(upc[0], oln); nbx = rlane(rxc[0], oln); nby = rlane(ryc[0], oln); nbz = rlane(rzc[0], oln); break;
                    case 1:  uj = rlane(upc[1], oln); nbx = rlane(rxc[1], oln); nby = rlane(ryc[1], oln); nbz = rlane(rzc[1], oln); break;
                    case 2:  uj = rlane(upc[2], oln); nbx = rlane(rxc[2], oln); nby = rlane(ryc[2], oln); nbz = rlane(rzc[2], oln); break;
                    default: uj = rlane(upc[3], oln); nbx = rlane(rxc[3], oln); nby = rlane(ryc[3], oln); nbz = rlane(rzc[3], oln); break;
                }

                // SALU free-column test (wave-uniform masks, no readlane)
                const unsigned long long fm =
                    (osl == 0 ? freem[0] : osl == 1 ? freem[1] : osl == 2 ? freem[2] : freem[3]);
                if ((fm >> oln) & 1ull) { jfin = j1; D = gmin; break; }

                // Owner bookkeeping (off critical path)
#pragma unroll
                for (int c = 0; c < 4; ++c)
                    if (c == osl && lane == oln) {
                        usedm |= (1 << c);
                        Tv[c] = gmin;
                    }

                // Next-iteration adjust, off the dist critical path
                const float gu = gmin - uj;
#pragma unroll
                for (int c = 0; c < 4; ++c) w[c] = gu - vv[c];

                bx = nbx; by = nby; bz = nbz;
                j0 = j1;
            }

            // Commit duals for tree columns: net amount = D_final - D_at_use
#pragma unroll
            for (int c = 0; c < 4; ++c)
                if ((usedm >> c) & 1) { vv[c] += Tv[c] - D; upc[c] += D - Tv[c]; }

            // Newly matched column leaves the free set
            {
                const int wsl = jfin >> 6;
                const unsigned long long bit = 1ull << (jfin & 63);
#pragma unroll
                for (int s = 0; s < 4; ++s)
                    if (s == wsl) freem[s] &= ~bit;
            }

            // Augment along alternating path
            int jc = jfin;
            while (true) {
                const int osl = jc >> 6, oln = jc & 63;
                int jw;
                switch (osl) {
                    case 0:  jw = rlanei(way[0], oln); break;
                    case 1:  jw = rlanei(way[1], oln); break;
                    case 2:  jw = rlanei(way[2], oln); break;
                    default: jw = rlanei(way[3], oln); break;
                }
                int np_; float nup, nrx, nry, nrz;
                if (jw < 0) {
                    np_ = i; nup = D; nrx = rootx; nry = rooty; nrz = rootz;
                } else {
                    const int wsl = jw >> 6, wln = jw & 63;
                    switch (wsl) {
                        case 0:  np_ = rlanei(pc[0], wln); nup = rlane(upc[0], wln); nrx = rlane(rxc[0], wln); nry = rlane(ryc[0], wln); nrz = rlane(rzc[0], wln); break;
                        case 1:  np_ = rlanei(pc[1], wln); nup = rlane(upc[1], wln); nrx = rlane(rxc[1], wln); nry = rlane(ryc[1], wln); nrz = rlane(rzc[1], wln); break;
                        case 2:  np_ = rlanei(pc[2], wln); nup = rlane(upc[2], wln); nrx = rlane(rxc[2], wln); nry = rlane(ryc[2], wln); nrz = rlane(rzc[2], wln); break;
                        default: np_ = rlanei(pc[3], wln); nup = rlane(upc[3], wln); nrx = rlane(rxc[3], wln); nry = rlane(ryc[3], wln); nrz = rlane(rzc[3], wln); break;
                    }
                }
#pragma unroll
                for (int c = 0; c < 4; ++c)
                    if (c == osl && lane == oln) {
                        pc[c] = np_; upc[c] = nup;
                        rxc[c] = nrx; ryc[c] = nry; rzc[c] = nrz;
                    }
                if (jw < 0) break;
                jc = jw;
            }
        }
    }

    // ---- Matched cost (coords column-attached; IEEE sqrt for final accuracy) ----
    float s = 0.f;
#pragma unroll
    for (int c = 0; c < 4; ++c) {
        float dx = rxc[c] - tx[c], dy = ryc[c] - ty[c], dz = rzc[c] - tz[c];
        s += sqrtf(dx * dx + dy * dy + dz * dz);
    }
#pragma unroll
    for (int off = 1; off < 64; off <<= 1) s += __shfl_xor(s, off, 64);
    if (lane == 0) atomicAdd(out, s / (float)NBATCH);
}

extern "C" void kernel_launch(void* const* d_in, const int* in_sizes, int n_in,
                              void* d_out, int out_size, void* d_ws, size_t ws_size,
                              hipStream_t stream) {
    const float* pred   = (const float*)d_in[0];
    const float* target = (const float*)d_in[1];
    float* out = (float*)d_out;

    zero_out_kernel<<<1, 64, 0, stream>>>(out, out_size);
    hungarian_wave<<<NBATCH, 64, 0, stream>>>(pred, target, out);
}

// Round 10
// 1830.615 us; speedup vs baseline: 3.2660x; 1.0966x over previous
//
#include <hip/hip_runtime.h>

#define NPTS 256
#define NBATCH 64
#define BIGF 1e30f
#define KBIG 0x7149F200u   // __float_as_uint(1e30f) & 0xFFFFFF00

__device__ __forceinline__ float rlane(float v, int l) {
    return __uint_as_float((unsigned int)__builtin_amdgcn_readlane((int)__float_as_uint(v), l));
}
__device__ __forceinline__ int rlanei(int v, int l) {
    return __builtin_amdgcn_readlane(v, l);
}
__device__ __forceinline__ float rawsqrt(float x) {
    return __builtin_amdgcn_sqrtf(x);
}

// Uniform-slot select (slot wave-uniform); cold paths only.
#define SEL4(a, s) ((s) == 0 ? a[0] : (s) == 1 ? a[1] : (s) == 2 ? a[2] : a[3])

#define DPP_UMIN(v, ctrl) \
    (min)((v), (unsigned int)__builtin_amdgcn_update_dpp( \
        (int)(v), (int)(v), (ctrl), 0xf, 0xf, false))

__global__ void zero_out_kernel(float* out, int n) {
    int i = blockIdx.x * blockDim.x + threadIdx.x;
    if (i < n) out[i] = 0.0f;
}

// One wave per batch; lane owns columns/rows {lane, 64+lane, 128+lane, 192+lane}.
// JV: column reduction -> greedy claim -> delta-accumulated Dijkstra searches.
// Hot-loop structure (R10): packed-key slack table kMv (no separate Mv/repack),
// used-column exclusion via vv=-BIGF / kMv=KBIG sentinels (no usedm test in
// loop), wave-reduce split into 4 DPP row-steps + 4 parallel readlanes + SALU
// min tree (replaces 2 row_bcast DPP + readlane: fewer dependent cross-lane ops).
__launch_bounds__(64, 1)
__global__ void hungarian_wave(const float* __restrict__ pred,
                               const float* __restrict__ target,
                               float* __restrict__ out) {
    const int b    = blockIdx.x;
    const int lane = threadIdx.x;

    const float* pb = pred   + (size_t)b * NPTS * 3;
    const float* tb = target + (size_t)b * NPTS * 3;

    float prx[4], pry[4], prz[4];      // pred (row) points, row = c*64+lane
    float tx[4], ty[4], tz[4];         // target (col) points, col = c*64+lane
    float vv[4], upc[4], Tv[4], w[4], vsave[4];
    float rxc[4], ryc[4], rzc[4];      // matched-row coords, column-attached
    unsigned int kMv[4];               // packed slack keys: (bits(M)&~0xFF)|col
    int   pc[4]  = {-1, -1, -1, -1};   // matched row per column (-1 = free)
    int   way[4];
    unsigned int colu[4];              // this lane's column ids
    unsigned long long freem[4];       // free-COLUMN masks (wave-uniform)

#pragma unroll
    for (int c = 0; c < 4; ++c) {
        int idx = c * 64 + lane;
        prx[c] = pb[idx * 3 + 0]; pry[c] = pb[idx * 3 + 1]; prz[c] = pb[idx * 3 + 2];
        tx[c]  = tb[idx * 3 + 0]; ty[c]  = tb[idx * 3 + 1]; tz[c]  = tb[idx * 3 + 2];
        upc[c] = 0.f; Tv[c] = 0.f; vsave[c] = 0.f;
        rxc[c] = 0.f; ryc[c] = 0.f; rzc[c] = 0.f;
        colu[c] = (unsigned int)idx;
        freem[c] = ~0ull;
    }

    // ---- Phase 1a: column reduction. vv[c] = min_r d(r, col), colrow = argmin ----
    float colmin[4] = {BIGF, BIGF, BIGF, BIGF};
    int   colrow[4] = {0, 0, 0, 0};
#pragma unroll
    for (int rs = 0; rs < 4; ++rs) {
        for (int rl = 0; rl < 64; ++rl) {
            float bx = rlane(prx[rs], rl), by = rlane(pry[rs], rl), bz = rlane(prz[rs], rl);
            int r = rs * 64 + rl;
#pragma unroll
            for (int c = 0; c < 4; ++c) {
                float dx = bx - tx[c], dy = by - ty[c], dz = bz - tz[c];
                float d = rawsqrt(dx * dx + dy * dy + dz * dz);
                if (d < colmin[c]) { colmin[c] = d; colrow[c] = r; }
            }
        }
    }
#pragma unroll
    for (int c = 0; c < 4; ++c) vv[c] = colmin[c];

    // ---- Phase 1b: greedy claim — column (ascending) claims its argmin row if free ----
    unsigned long long frm[4];         // free-row masks (wave-uniform values)
    frm[0] = frm[1] = frm[2] = frm[3] = ~0ull;
#pragma unroll
    for (int cs = 0; cs < 4; ++cs) {
        for (int l = 0; l < 64; ++l) {
            int r = rlanei(colrow[cs], l);
            int rs = r >> 6, rl2 = r & 63;
            unsigned long long bit = 1ull << rl2;
            bool free_row = (SEL4(frm, rs) & bit) != 0ull;
            if (free_row) {
#pragma unroll
                for (int s = 0; s < 4; ++s)
                    if (s == rs) frm[s] &= ~bit;
                float bx, by, bz;
                switch (rs) {
                    case 0:  bx = rlane(prx[0], rl2); by = rlane(pry[0], rl2); bz = rlane(prz[0], rl2); break;
                    case 1:  bx = rlane(prx[1], rl2); by = rlane(pry[1], rl2); bz = rlane(prz[1], rl2); break;
                    case 2:  bx = rlane(prx[2], rl2); by = rlane(pry[2], rl2); bz = rlane(prz[2], rl2); break;
                    default: bx = rlane(prx[3], rl2); by = rlane(pry[3], rl2); bz = rlane(prz[3], rl2); break;
                }
                if (lane == l) {
                    pc[cs] = r; upc[cs] = 0.f;
                    rxc[cs] = bx; ryc[cs] = by; rzc[cs] = bz;
                }
#pragma unroll
                for (int s = 0; s < 4; ++s)
                    if (s == cs) freem[s] &= ~(1ull << l);   // column cs*64+l matched
            }
        }
    }

    // ---- Phase 2: Dijkstra shortest-path for remaining free rows ----
#pragma unroll
    for (int is = 0; is < 4; ++is) {
        unsigned long long m = frm[is];
        while (m) {
            const int il = (int)__builtin_ctzll(m);
            m &= (m - 1);
            const int i = is * 64 + il;

            float rootx, rooty, rootz;
            switch (is) {
                case 0:  rootx = rlane(prx[0], il); rooty = rlane(pry[0], il); rootz = rlane(prz[0], il); break;
                case 1:  rootx = rlane(prx[1], il); rooty = rlane(pry[1], il); rootz = rlane(prz[1], il); break;
                case 2:  rootx = rlane(prx[2], il); rooty = rlane(pry[2], il); rootz = rlane(prz[2], il); break;
                default: rootx = rlane(prx[3], il); rooty = rlane(pry[3], il); rootz = rlane(prz[3], il); break;
            }

#pragma unroll
            for (int c = 0; c < 4; ++c) {
                kMv[c] = KBIG | colu[c];
                w[c]   = -vv[c];
            }
            int usedm = 0;

            float bx = rootx, by = rooty, bz = rootz;
            int j0 = -1;
            int jfin = 0;
            float D = 0.f;

            while (true) {
                // Relax all columns; used columns are naturally excluded:
                // w = gu + BIGF -> cand = BIGF exactly -> kc == kMv -> no update.
#pragma unroll
                for (int c = 0; c < 4; ++c) {
                    float dx = bx - tx[c], dy = by - ty[c], dz = bz - tz[c];
                    float d = rawsqrt(dx * dx + dy * dy + dz * dz);
                    float cand = d + w[c];              // == d - ukey - vv[c]
                    unsigned int kc = (__float_as_uint(cand) & 0xFFFFFF00u) | colu[c];
                    if (kc < kMv[c]) { kMv[c] = kc; way[c] = j0; }
                }
                unsigned int v = (min)((min)(kMv[0], kMv[1]), (min)(kMv[2], kMv[3]));
                // 4 DPP row-steps -> row minima in lanes 15/31/47/63
                v = DPP_UMIN(v, 0x111);   // row_shr:1
                v = DPP_UMIN(v, 0x112);   // row_shr:2
                v = DPP_UMIN(v, 0x114);   // row_shr:4
                v = DPP_UMIN(v, 0x118);   // row_shr:8
                const unsigned int r0 = (unsigned int)rlanei((int)v, 15);
                const unsigned int r1 = (unsigned int)rlanei((int)v, 31);
                const unsigned int r2 = (unsigned int)rlanei((int)v, 47);
                const unsigned int r3 = (unsigned int)rlanei((int)v, 63);
                const unsigned int kk = (min)((min)(r0, r1), (min)(r2, r3));

                const int   j1   = (int)(kk & 0xFFu);
                const float gmin = __uint_as_float(kk & 0xFFFFFF00u);
                const int osl = j1 >> 6, oln = j1 & 63;

                // Speculative state readlanes (issued before the exit branch)
                float uj, nbx, nby, nbz;
                switch (osl) {
                    case 0:  uj = rlane(upc[0], oln); nbx = rlane(rxc[0], oln); nby = rlane(ryc[0], oln); nbz = rlane(rzc[0], oln); break;
                    case 1:  uj = rlane(upc[1], oln); nbx = rlane(rxc[1], oln); nby = rlane(ryc[1], oln); nbz = rlane(rzc[1], oln); break;
                    case 2:  uj = rlane(upc[2], oln); nbx = rlane(rxc[2], oln); nby = rlane(ryc[2], oln); nbz = rlane(rzc[2], oln); break;
                    default: uj = rlane(upc[3], oln); nbx = rlane(rxc[3], oln); nby = rlane(ryc[3], oln); nbz = rlane(rzc[3], oln); break;
                }

                // SALU free-column test (wave-uniform masks, no readlane)
                const unsigned long long fm =
                    (osl == 0 ? freem[0] : osl == 1 ? freem[1] : osl == 2 ? freem[2] : freem[3]);
                if ((fm >> oln) & 1ull) { jfin = j1; D = gmin; break; }

                // Owner bookkeeping (off critical path): mark used via sentinels
#pragma unroll
                for (int c = 0; c < 4; ++c)
                    if (c == osl && lane == oln) {
                        usedm |= (1 << c);
                        Tv[c] = gmin;
                        vsave[c] = vv[c];
                        vv[c] = -BIGF;                 // -> w = +BIGF -> excluded
                        kMv[c] = KBIG | colu[c];       // cand==BIGF -> kc==kMv -> frozen
                    }

                // Next-iteration adjust, off the dist critical path
                const float gu = gmin - uj;
#pragma unroll
                for (int c = 0; c < 4; ++c) w[c] = gu - vv[c];

                bx = nbx; by = nby; bz = nbz;
                j0 = j1;
            }

            // Commit duals for tree columns: net amount = D_final - D_at_use
#pragma unroll
            for (int c = 0; c < 4; ++c)
                if ((usedm >> c) & 1) {
                    vv[c] = vsave[c] + Tv[c] - D;
                    upc[c] += D - Tv[c];
                }

            // Newly matched column leaves the free set
            {
                const int wsl = jfin >> 6;
                const unsigned long long bit = 1ull << (jfin & 63);
#pragma unroll
                for (int s = 0; s < 4; ++s)
                    if (s == wsl) freem[s] &= ~bit;
            }

            // Augment along alternating path
            int jc = jfin;
            while (true) {
                const int osl = jc >> 6, oln = jc & 63;
                int jw;
                switch (osl) {
                    case 0:  jw = rlanei(way[0], oln); break;
                    case 1:  jw = rlanei(way[1], oln); break;
                    case 2:  jw = rlanei(way[2], oln); break;
                    default: jw = rlanei(way[3], oln); break;
                }
                int np_; float nup, nrx, nry, nrz;
                if (jw < 0) {
                    np_ = i; nup = D; nrx = rootx; nry = rooty; nrz = rootz;
                } else {
                    const int wsl = jw >> 6, wln = jw & 63;
                    switch (wsl) {
                        case 0:  np_ = rlanei(pc[0], wln); nup = rlane(upc[0], wln); nrx = rlane(rxc[0], wln); nry = rlane(ryc[0], wln); nrz = rlane(rzc[0], wln); break;
                        case 1:  np_ = rlanei(pc[1], wln); nup = rlane(upc[1], wln); nrx = rlane(rxc[1], wln); nry = rlane(ryc[1], wln); nrz = rlane(rzc[1], wln); break;
                        case 2:  np_ = rlanei(pc[2], wln); nup = rlane(upc[2], wln); nrx = rlane(rxc[2], wln); nry = rlane(ryc[2], wln); nrz = rlane(rzc[2], wln); break;
                        default: np_ = rlanei(pc[3], wln); nup = rlane(upc[3], wln); nrx = rlane(rxc[3], wln); nry = rlane(ryc[3], wln); nrz = rlane(rzc[3], wln); break;
                    }
                }
#pragma unroll
                for (int c = 0; c < 4; ++c)
                    if (c == osl && lane == oln) {
                        pc[c] = np_; upc[c] = nup;
                        rxc[c] = nrx; ryc[c] = nry; rzc[c] = nrz;
                    }
                if (jw < 0) break;
                jc = jw;
            }
        }
    }

    // ---- Matched cost (coords column-attached; IEEE sqrt for final accuracy) ----
    float s = 0.f;
#pragma unroll
    for (int c = 0; c < 4; ++c) {
        float dx = rxc[c] - tx[c], dy = ryc[c] - ty[c], dz = rzc[c] - tz[c];
        s += sqrtf(dx * dx + dy * dy + dz * dz);
    }
#pragma unroll
    for (int off = 1; off < 64; off <<= 1) s += __shfl_xor(s, off, 64);
    if (lane == 0) atomicAdd(out, s / (float)NBATCH);
}

extern "C" void kernel_launch(void* const* d_in, const int* in_sizes, int n_in,
                              void* d_out, int out_size, void* d_ws, size_t ws_size,
                              hipStream_t stream) {
    const float* pred   = (const float*)d_in[0];
    const float* target = (const float*)d_in[1];
    float* out = (float*)d_out;

    zero_out_kernel<<<1, 64, 0, stream>>>(out, out_size);
    hungarian_wave<<<NBATCH, 64, 0, stream>>>(pred, target, out);
}